// Round 19
// baseline (59.706 us; speedup 1.0000x reference)
//
#include <hip/hip_runtime.h>
#include <hip/hip_bf16.h>

// RBF kernel matrix: out[i][j] = exp(-gamma * max(x2[i] + y2[j] - 2*x.y, 0))
//
// Round 19: r18 persistence + DOUBLE the waves/CU (8 -> 16).
// Issue-rate theory: per-CU write drain at 6.9 TB/s needs ~11 B/cy; a wave
// issues one 64B store per ~60cy sub-tile -> 8 waves/CU = ~8.5 B/cy, which
// matches the measured ~78%-of-fill plateau. Fix: 1 Y tile per block
// (32 KB LDS) -> 4 blocks/CU x 4 waves = 16 waves/CU (~17 B/cy capability).
// To fit the 128-VGPR cap (launch_bounds(256,4)): A frags stay hoisted
// (64 VGPR, direct-from-global frag-linear); B frags read per-n2 from LDS
// (16 VGPR transient; n2-outer / m2-inner). IPB=4 panel sweep and the
// zero-post-sync-barrier discipline are unchanged from r18.
// 3 MFMA passes (hh + loY*hiX + hiY*loX), drop lo*lo (~1e-21 abs err).

#define DD 64
#define BM 128
#define BN 128
#define IPB 4

typedef __attribute__((ext_vector_type(8))) short short8;
typedef __attribute__((ext_vector_type(4))) float f32x4;

#if __has_builtin(__builtin_amdgcn_exp2f)
#define EXP2(x) __builtin_amdgcn_exp2f(x)
#else
#define EXP2(x) exp2f(x)
#endif

__device__ __forceinline__ unsigned short f2bf_rne(float f) {
  unsigned u = __float_as_uint(f);
  unsigned r = u + 0x7FFFu + ((u >> 16) & 1u);
  return (unsigned short)(r >> 16);
}

// X fragment-linear index (short8 units): panel p, k-step s, row-block rb.
// Lane hg*16+lr holds row rb*16+lr, k = s*32+hg*8 .. +8.  (r5-verified)
__device__ __forceinline__ long fidx(int p, int s, int rb) {
  return ((((long)p * 2 + s) * 8) + rb) * 64;
}

// ---------------- prep: norms + X->frag-linear, Y->swizzled row images ------
__global__ __launch_bounds__(256)
void prep_mix2(const float* __restrict__ X, const float* __restrict__ Y,
               short8* __restrict__ XHf, short8* __restrict__ XLf,
               unsigned short* __restrict__ YHg, unsigned short* __restrict__ YLg,
               float* __restrict__ xsq, float* __restrict__ ysq, int n) {
  int t = blockIdx.x * 256 + threadIdx.x;
  int row_g = t >> 3;
  int chunk = t & 7;                 // 8 consecutive k per thread
  int isX = (row_g < n);
  int r = isX ? row_g : row_g - n;
  const float* src = (isX ? X : Y) + (long)r * DD + chunk * 8;
  float4 v0 = ((const float4*)src)[0];
  float4 v1 = ((const float4*)src)[1];
  float f[8] = {v0.x, v0.y, v0.z, v0.w, v1.x, v1.y, v1.z, v1.w};

  short8 h8, l8;
  float ss = 0.f;
#pragma unroll
  for (int q = 0; q < 8; ++q) {
    unsigned short h = f2bf_rne(f[q]);
    float hv = __uint_as_float(((unsigned)h) << 16);
    h8[q] = (short)h;
    l8[q] = (short)f2bf_rne(f[q] - hv);
    ss = fmaf(f[q], f[q], ss);
  }
  if (isX) {
    int pn = r >> 7, rb = (r >> 4) & 7, lr = r & 15;
    int s = chunk >> 2, hg = chunk & 3;
    long o = fidx(pn, s, rb) + hg * 16 + lr;
    XHf[o] = h8;
    XLf[o] = l8;
  } else {
    int sw = (chunk * 16) ^ ((r & 7) << 4);   // swizzled byte offset (verified)
    *(short8*)((char*)YHg + (long)r * 128 + sw) = h8;
    *(short8*)((char*)YLg + (long)r * 128 + sw) = l8;
  }
  ss += __shfl_xor(ss, 1);
  ss += __shfl_xor(ss, 2);
  ss += __shfl_xor(ss, 4);
  if (chunk == 0) (isX ? xsq : ysq)[r] = ss;
}

// ---------------- main: 16 waves/CU persistent i-sweep ----------------------
__global__ __launch_bounds__(256, 4)
void rbf_w16(const short8* __restrict__ XHf, const short8* __restrict__ XLf,
             const unsigned short* __restrict__ YHg, const unsigned short* __restrict__ YLg,
             const float* __restrict__ gptr,
             const float* __restrict__ xsq, const float* __restrict__ ysq,
             float* __restrict__ Out, int mcols) {
  // [0,16K) YH  [16K,32K) YL — staged once, never rewritten
  __shared__ __align__(128) char lds[32768];

  const int tid = threadIdx.x;
  const int lane = tid & 63;
  const int wid = tid >> 6;        // 0..3
  const int ig0 = blockIdx.y * IPB;              // first X panel
  const long j0 = (long)blockIdx.x * BN;         // 128-col strip

  // ---- prologue DMA: YH, YL (16 KB each)
#pragma unroll
  for (int t4 = 0; t4 < 2; ++t4) {
    const char* src = (t4 ? (const char*)YLg : (const char*)YHg) + j0 * 128;
#pragma unroll
    for (int it = 0; it < 4; ++it) {
      int off = it * 4096 + wid * 1024;           // wave-uniform
      __builtin_amdgcn_global_load_lds(
          (const __attribute__((address_space(1))) void*)(src + off + lane * 16),
          (__attribute__((address_space(3))) void*)(lds + t4 * 16384 + off),
          16, 0, 0);
    }
  }

  const int wr = wid >> 1, wc = wid & 1;
  const int lr = lane & 15;
  const int hg = lane >> 4;        // 0..3

  // ---- A-frags for panel 0 (direct from global; overlaps the Y DMA)
  short8 afh[2][4], afl[2][4];     // [s][m2]
#pragma unroll
  for (int s = 0; s < 2; ++s)
#pragma unroll
    for (int q = 0; q < 4; ++q) {
      afh[s][q] = XHf[fidx(ig0, s, wr * 4 + q) + lane];
      afl[s][q] = XLf[fidx(ig0, s, wr * 4 + q) + lane];
    }

  const float g = *gptr;
  const float cf = -g * 1.4426950408889634f;   // -gamma*log2(e)
  const float nc2 = -2.0f * cf;

  __syncthreads();   // drains prologue loads only (no stores yet) — cheap

  for (int p = 0; p < IPB; ++p) {
    const int ip = ig0 + p;
    const long i0 = (long)ip * BM;
    float cxr[4];
#pragma unroll
    for (int m2 = 0; m2 < 4; ++m2) cxr[m2] = cf * xsq[i0 + wr * 64 + m2 * 16 + lr];

    // ---- n2-outer: read B frags per col-group (16 VGPR transient)
#pragma unroll
    for (int n2 = 0; n2 < 4; ++n2) {
      short8 bfh[2], bfl[2];
#pragma unroll
      for (int s = 0; s < 2; ++s) {
        int rb = wc * 64 + n2 * 16 + lr;
        int ob = (s * 64 + hg * 16) ^ ((rb & 7) << 4);
        bfh[s] = *(const short8*)(lds + rb * 128 + ob);
        bfl[s] = *(const short8*)(lds + 16384 + rb * 128 + ob);
      }
      float4 yq = *(const float4*)&ysq[j0 + wc * 64 + n2 * 16 + hg * 4];
      float cy[4] = {cf * yq.x, cf * yq.y, cf * yq.z, cf * yq.w};

#pragma unroll
      for (int m2 = 0; m2 < 4; ++m2) {
        f32x4 a = (f32x4){0.f, 0.f, 0.f, 0.f};
#pragma unroll
        for (int s = 0; s < 2; ++s) {
          a = __builtin_amdgcn_mfma_f32_16x16x32_bf16(bfh[s], afh[s][m2], a, 0, 0, 0);
          a = __builtin_amdgcn_mfma_f32_16x16x32_bf16(bfh[s], afl[s][m2], a, 0, 0, 0);
          a = __builtin_amdgcn_mfma_f32_16x16x32_bf16(bfl[s], afh[s][m2], a, 0, 0, 0);
        }
        long row = i0 + wr * 64 + m2 * 16 + lr;
        float* op = Out + row * (long)mcols + j0 + wc * 64 + n2 * 16 + hg * 4;
        float o[4];
        o[0] = EXP2(fminf(fmaf(nc2, a[0], cxr[m2] + cy[0]), 0.f));
        o[1] = EXP2(fminf(fmaf(nc2, a[1], cxr[m2] + cy[1]), 0.f));
        o[2] = EXP2(fminf(fmaf(nc2, a[2], cxr[m2] + cy[2]), 0.f));
        o[3] = EXP2(fminf(fmaf(nc2, a[3], cxr[m2] + cy[3]), 0.f));
        *(float4*)op = *(float4*)o;
        __builtin_amdgcn_sched_barrier(0);   // pin store spacing
      }
    }

    // ---- load A(p+1) frags (independent L2 loads; no barrier, no LDS)
    if (p + 1 < IPB) {
#pragma unroll
      for (int s = 0; s < 2; ++s)
#pragma unroll
        for (int q = 0; q < 4; ++q) {
          afh[s][q] = XHf[fidx(ip + 1, s, wr * 4 + q) + lane];
          afl[s][q] = XLf[fidx(ip + 1, s, wr * 4 + q) + lane];
        }
    }
  }
}

// ---------------- fallback (proven round-2 path) ---------------------------
__global__ __launch_bounds__(256)
void prep_sq(const float* __restrict__ X, const float* __restrict__ Y,
             float* __restrict__ xsq, float* __restrict__ ysq, int n) {
  int t = blockIdx.x * 256 + threadIdx.x;
  int row = t >> 4;
  int c = t & 15;
  const float* src;
  float* dst;
  if (row < n) { src = X + (long)row * DD; dst = xsq + row; }
  else         { src = Y + (long)(row - n) * DD; dst = ysq + (row - n); }
  float4 v = ((const float4*)src)[c];
  float s = v.x * v.x + v.y * v.y + v.z * v.z + v.w * v.w;
  s += __shfl_xor(s, 1);
  s += __shfl_xor(s, 2);
  s += __shfl_xor(s, 4);
  s += __shfl_xor(s, 8);
  if (c == 0) *dst = s;
}

__global__ __launch_bounds__(256, 2)
void rbf_mfma_fb(const float* __restrict__ X, const float* __restrict__ Y,
                 const float* __restrict__ gptr,
                 const float* __restrict__ xsq, const float* __restrict__ ysq,
                 float* __restrict__ Out, int mcols) {
  __shared__ unsigned short XH[128 * DD], XL[128 * DD];
  __shared__ unsigned short YH[128 * DD], YL[128 * DD];
  const int tid = threadIdx.x;
  const long i0 = (long)blockIdx.y * 128;
  const long j0 = (long)blockIdx.x * 128;
#pragma unroll
  for (int it = 0; it < 16; ++it) {
    int e = it * 256 + tid;
    int half = e >> 11;
    int idx = e & 2047;
    int row = idx >> 4;
    int c4 = idx & 15;
    const float* src = half ? (Y + (j0 + row) * DD) : (X + (i0 + row) * DD);
    float4 v = ((const float4*)src)[c4];
    float f[4] = {v.x, v.y, v.z, v.w};
    unsigned short h[4], l[4];
#pragma unroll
    for (int q = 0; q < 4; ++q) {
      h[q] = f2bf_rne(f[q]);
      float hv = __uint_as_float(((unsigned)h[q]) << 16);
      l[q] = f2bf_rne(f[q] - hv);
    }
    int sw = (c4 * 8) ^ ((row & 7) << 4);
    unsigned short* Ht = half ? YH : XH;
    unsigned short* Lt = half ? YL : XL;
    *(ushort4*)((char*)Ht + row * 128 + sw) = make_ushort4(h[0], h[1], h[2], h[3]);
    *(ushort4*)((char*)Lt + row * 128 + sw) = make_ushort4(l[0], l[1], l[2], l[3]);
  }
  __syncthreads();
  const int lane = tid & 63;
  const int wid = tid >> 6;
  const int wr = wid >> 1, wc = wid & 1;
  const int lr = lane & 15;
  const int hg = lane >> 4;
  f32x4 acc[4][4];
#pragma unroll
  for (int a = 0; a < 4; ++a)
#pragma unroll
    for (int c = 0; c < 4; ++c) acc[a][c] = (f32x4){0.f, 0.f, 0.f, 0.f};
  const unsigned short* At[3] = {XH, XL, XH};
  const unsigned short* Bt[3] = {YH, YH, YL};
#pragma unroll
  for (int p = 0; p < 3; ++p) {
#pragma unroll
    for (int s = 0; s < 2; ++s) {
      const int kbyte = s * 64 + hg * 16;
      short8 af[4], bfv[4];
#pragma unroll
      for (int m2 = 0; m2 < 4; ++m2) {
        int row = wr * 64 + m2 * 16 + lr;
        af[m2] = *(const short8*)((const char*)At[p] + row * 128 + (kbyte ^ ((row & 7) << 4)));
      }
#pragma unroll
      for (int n2 = 0; n2 < 4; ++n2) {
        int row = wc * 64 + n2 * 16 + lr;
        bfv[n2] = *(const short8*)((const char*)Bt[p] + row * 128 + (kbyte ^ ((row & 7) << 4)));
      }
#pragma unroll
      for (int m2 = 0; m2 < 4; ++m2)
#pragma unroll
        for (int n2 = 0; n2 < 4; ++n2)
          acc[m2][n2] = __builtin_amdgcn_mfma_f32_16x16x32_bf16(af[m2], bfv[n2], acc[m2][n2], 0, 0, 0);
    }
  }
  const float g = *gptr;
  float yv[4];
#pragma unroll
  for (int n2 = 0; n2 < 4; ++n2) yv[n2] = ysq[j0 + wc * 64 + n2 * 16 + lr];
#pragma unroll
  for (int m2 = 0; m2 < 4; ++m2) {
#pragma unroll
    for (int j = 0; j < 4; ++j) {
      long row = i0 + wr * 64 + m2 * 16 + hg * 4 + j;
      float xr = xsq[row];
      float* op = Out + row * (long)mcols + j0 + wc * 64 + lr;
#pragma unroll
      for (int n2 = 0; n2 < 4; ++n2) {
        float d = fmaxf(xr + yv[n2] - 2.0f * acc[m2][n2][j], 0.f);
        op[n2 * 16] = __expf(-g * d);
      }
    }
  }
}

extern "C" void kernel_launch(void* const* d_in, const int* in_sizes, int n_in,
                              void* d_out, int out_size, void* d_ws, size_t ws_size,
                              hipStream_t stream) {
  const float* x = (const float*)d_in[0];
  const float* y = (const float*)d_in[1];
  const float* g = (const float*)d_in[2];
  float* out = (float*)d_out;

  const int n = in_sizes[0] / DD;   // 8192
  const int m = in_sizes[1] / DD;   // 8192

  const size_t split_bytes = (size_t)(n + m) * DD * 2 * sizeof(unsigned short);
  const size_t needed = split_bytes + (size_t)(n + m) * sizeof(float);

  if (ws_size >= needed && (n % (BM * IPB)) == 0 && (m % BN) == 0) {
    short8* XHf = (short8*)d_ws;                       // n*DD/8 short8
    short8* XLf = XHf + (size_t)n * DD / 8;
    unsigned short* YHg = (unsigned short*)(XLf + (size_t)n * DD / 8);
    unsigned short* YLg = YHg + (size_t)m * DD;
    float* xsq = (float*)(YLg + (size_t)m * DD);
    float* ysq = xsq + n;
    prep_mix2<<<(n + m) * 8 / 256, 256, 0, stream>>>(x, y, XHf, XLf, YHg, YLg, xsq, ysq, n);
    dim3 grid(m / BN, n / (BM * IPB));   // 64 x 16 = 1024 blocks (4/CU)
    rbf_w16<<<grid, 256, 0, stream>>>(XHf, XLf, YHg, YLg, g, xsq, ysq, out, m);
  } else {
    float* xsq = (float*)d_ws;
    float* ysq = xsq + n;
    prep_sq<<<(n + m) / 16, 256, 0, stream>>>(x, y, xsq, ysq, n);
    dim3 grid2(m / 128, n / 128);
    rbf_mfma_fb<<<grid2, 256, 0, stream>>>(x, y, g, xsq, ysq, out, m);
  }
}

// Round 21
// 49.304 us; speedup vs baseline: 1.2110x; 1.2110x over previous
//
#include <hip/hip_runtime.h>
#include <hip/hip_bf16.h>

// RBF kernel matrix: out[i][j] = exp(-gamma * max(x2[i] + y2[j] - 2*x.y, 0))
//
// Round 21: r20 with the store-address fix (op + n2*16 — r20 wrote all four
// n2 sub-tiles to the same address; failure was a porting bug, not physics).
// FP16 ASYMMETRIC 2-PASS split: x.y ~= xh.(yh + yl), drop xl.y
// (|xl| <= 2^-11|x| -> sigma(delta sq_dist) ~ 4.5e-3 -> ~3e-21 abs out err).
// fp16 products exact in fp32 MFMA accumulator. Sub-tile: 4 MFMA (was 6).
// r18 structure otherwise: persistent i-sweep (IPB=4), Y strip staged once
// (64 KB, never rewritten), A-frags direct-from-global frag-linear (hi only,
// 32 VGPR), zero post-sync barriers, fenced sub-tile stores.

#define DD 64
#define BM 128
#define BN 128
#define IPB 4

typedef __attribute__((ext_vector_type(8))) _Float16 half8;
typedef __attribute__((ext_vector_type(4))) float f32x4;

#if __has_builtin(__builtin_amdgcn_exp2f)
#define EXP2(x) __builtin_amdgcn_exp2f(x)
#else
#define EXP2(x) exp2f(x)
#endif

// X fragment-linear index (half8 units): panel p, k-step s, row-block rb.
// Lane hg*16+lr holds row rb*16+lr, k = s*32+hg*8 .. +8.  (r5-verified)
__device__ __forceinline__ long fidx(int p, int s, int rb) {
  return ((((long)p * 2 + s) * 8) + rb) * 64;
}

// ---------------- prep: norms + X->fp16 frag-linear, Y->fp16 hi/lo images ---
__global__ __launch_bounds__(256)
void prep_f16(const float* __restrict__ X, const float* __restrict__ Y,
              half8* __restrict__ XHf,
              unsigned short* __restrict__ YHg, unsigned short* __restrict__ YLg,
              float* __restrict__ xsq, float* __restrict__ ysq, int n) {
  int t = blockIdx.x * 256 + threadIdx.x;
  int row_g = t >> 3;
  int chunk = t & 7;                 // 8 consecutive k per thread
  int isX = (row_g < n);
  int r = isX ? row_g : row_g - n;
  const float* src = (isX ? X : Y) + (long)r * DD + chunk * 8;
  float4 v0 = ((const float4*)src)[0];
  float4 v1 = ((const float4*)src)[1];
  float f[8] = {v0.x, v0.y, v0.z, v0.w, v1.x, v1.y, v1.z, v1.w};

  half8 h8, l8;
  float ss = 0.f;
#pragma unroll
  for (int q = 0; q < 8; ++q) {
    _Float16 h = (_Float16)f[q];          // RNE fp32->fp16
    h8[q] = h;
    l8[q] = (_Float16)(f[q] - (float)h);  // residual
    ss = fmaf(f[q], f[q], ss);
  }
  if (isX) {
    int pn = r >> 7, rb = (r >> 4) & 7, lr = r & 15;
    int s = chunk >> 2, hg = chunk & 3;
    XHf[fidx(pn, s, rb) + hg * 16 + lr] = h8;   // only hi needed for X
  } else {
    int sw = (chunk * 16) ^ ((r & 7) << 4);     // swizzled byte offset (verified)
    *(half8*)((char*)YHg + (long)r * 128 + sw) = h8;
    *(half8*)((char*)YLg + (long)r * 128 + sw) = l8;
  }
  ss += __shfl_xor(ss, 1);
  ss += __shfl_xor(ss, 2);
  ss += __shfl_xor(ss, 4);
  if (chunk == 0) (isX ? xsq : ysq)[r] = ss;
}

// ---------------- main: persistent i-sweep, fp16 2-pass, fenced stores ------
__global__ __launch_bounds__(256, 2)
void rbf_f16(const half8* __restrict__ XHf,
             const unsigned short* __restrict__ YHg, const unsigned short* __restrict__ YLg,
             const float* __restrict__ gptr,
             const float* __restrict__ xsq, const float* __restrict__ ysq,
             float* __restrict__ Out, int mcols) {
  // [0,16K) Y0H  [16K,32K) Y0L  [32K,48K) Y1H  [48K,64K) Y1L — never rewritten
  __shared__ __align__(128) char lds[65536];

  const int tid = threadIdx.x;
  const int lane = tid & 63;
  const int wid = tid >> 6;        // 0..3
  const int ig0 = blockIdx.y * IPB;              // first X panel
  const long j0 = (long)blockIdx.x * (2 * BN);   // 256-col strip

  // ---- prologue DMA: Y0H, Y0L, Y1H, Y1L (16 KB each)
  const char* srcs[4] = {(const char*)YHg + j0 * 128,        (const char*)YLg + j0 * 128,
                         (const char*)YHg + (j0 + BN) * 128, (const char*)YLg + (j0 + BN) * 128};
#pragma unroll
  for (int t4 = 0; t4 < 4; ++t4) {
#pragma unroll
    for (int it = 0; it < 4; ++it) {
      int off = it * 4096 + wid * 1024;           // wave-uniform
      __builtin_amdgcn_global_load_lds(
          (const __attribute__((address_space(1))) void*)(srcs[t4] + off + lane * 16),
          (__attribute__((address_space(3))) void*)(lds + t4 * 16384 + off),
          16, 0, 0);
    }
  }

  const int wr = wid >> 1, wc = wid & 1;
  const int lr = lane & 15;
  const int hg = lane >> 4;        // 0..3

  // ---- A-frags (hi only) for panel 0: direct from global, frag-linear
  half8 afh[2][4];                 // [s][m2] — 32 VGPR
#pragma unroll
  for (int s = 0; s < 2; ++s)
#pragma unroll
    for (int q = 0; q < 4; ++q)
      afh[s][q] = XHf[fidx(ig0, s, wr * 4 + q) + lane];

  const float g = *gptr;
  const float cf = -g * 1.4426950408889634f;   // -gamma*log2(e)
  const float nc2 = -2.0f * cf;

  __syncthreads();   // drains prologue loads only (no stores yet) — cheap

  for (int p = 0; p < IPB; ++p) {
    const int ip = ig0 + p;
    const long i0 = (long)ip * BM;
    float cxr[4];
#pragma unroll
    for (int m2 = 0; m2 < 4; ++m2) cxr[m2] = cf * xsq[i0 + wr * 64 + m2 * 16 + lr];

#pragma unroll
    for (int t = 0; t < 2; ++t) {
      const long jt = j0 + (long)t * BN;
      const int yb = t * 32768;

      // hoist B(t) frags (wave-local LDS reads; data never overwritten)
      half8 bfh[2][4], bfl[2][4];   // [s][n2]
#pragma unroll
      for (int s = 0; s < 2; ++s)
#pragma unroll
        for (int q = 0; q < 4; ++q) {
          int rb = wc * 64 + q * 16 + lr;
          int ob = (s * 64 + hg * 16) ^ ((rb & 7) << 4);
          bfh[s][q] = *(const half8*)(lds + yb + rb * 128 + ob);
          bfl[s][q] = *(const half8*)(lds + yb + 16384 + rb * 128 + ob);
        }

      float4 cyv[4];
#pragma unroll
      for (int n2 = 0; n2 < 4; ++n2) {
        float4 yq = *(const float4*)&ysq[jt + wc * 64 + n2 * 16 + hg * 4];
        cyv[n2] = make_float4(cf * yq.x, cf * yq.y, cf * yq.z, cf * yq.w);
      }

      // 16 fenced sub-tiles: 4 MFMAs + 4 exp + 1 float4 store each
#pragma unroll
      for (int m2 = 0; m2 < 4; ++m2) {
        long row = i0 + wr * 64 + m2 * 16 + lr;
        float* op = Out + row * (long)mcols + jt + wc * 64 + hg * 4;
#pragma unroll
        for (int n2 = 0; n2 < 4; ++n2) {
          f32x4 a = (f32x4){0.f, 0.f, 0.f, 0.f};
#pragma unroll
          for (int s = 0; s < 2; ++s) {
            a = __builtin_amdgcn_mfma_f32_16x16x32_f16(bfh[s][n2], afh[s][m2], a, 0, 0, 0);
            a = __builtin_amdgcn_mfma_f32_16x16x32_f16(bfl[s][n2], afh[s][m2], a, 0, 0, 0);
          }
          float o[4];
          o[0] = EXP2(fminf(fmaf(nc2, a[0], cxr[m2] + cyv[n2].x), 0.f));
          o[1] = EXP2(fminf(fmaf(nc2, a[1], cxr[m2] + cyv[n2].y), 0.f));
          o[2] = EXP2(fminf(fmaf(nc2, a[2], cxr[m2] + cyv[n2].z), 0.f));
          o[3] = EXP2(fminf(fmaf(nc2, a[3], cxr[m2] + cyv[n2].w), 0.f));
          *(float4*)(op + n2 * 16) = *(float4*)o;   // FIX: + n2*16 (r20 bug)
          __builtin_amdgcn_sched_barrier(0);   // pin store spacing
        }
      }
    }

    // ---- load A(p+1) frags (independent L2 loads; no barrier, no LDS)
    if (p + 1 < IPB) {
#pragma unroll
      for (int s = 0; s < 2; ++s)
#pragma unroll
        for (int q = 0; q < 4; ++q)
          afh[s][q] = XHf[fidx(ip + 1, s, wr * 4 + q) + lane];
    }
  }
}

// ---------------- fallback (proven round-2 path, bf16 3-pass) ---------------
typedef __attribute__((ext_vector_type(8))) short short8;

__device__ __forceinline__ unsigned short f2bf_rne(float f) {
  unsigned u = __float_as_uint(f);
  unsigned r = u + 0x7FFFu + ((u >> 16) & 1u);
  return (unsigned short)(r >> 16);
}

__global__ __launch_bounds__(256)
void prep_sq(const float* __restrict__ X, const float* __restrict__ Y,
             float* __restrict__ xsq, float* __restrict__ ysq, int n) {
  int t = blockIdx.x * 256 + threadIdx.x;
  int row = t >> 4;
  int c = t & 15;
  const float* src;
  float* dst;
  if (row < n) { src = X + (long)row * DD; dst = xsq + row; }
  else         { src = Y + (long)(row - n) * DD; dst = ysq + (row - n); }
  float4 v = ((const float4*)src)[c];
  float s = v.x * v.x + v.y * v.y + v.z * v.z + v.w * v.w;
  s += __shfl_xor(s, 1);
  s += __shfl_xor(s, 2);
  s += __shfl_xor(s, 4);
  s += __shfl_xor(s, 8);
  if (c == 0) *dst = s;
}

__global__ __launch_bounds__(256, 2)
void rbf_mfma_fb(const float* __restrict__ X, const float* __restrict__ Y,
                 const float* __restrict__ gptr,
                 const float* __restrict__ xsq, const float* __restrict__ ysq,
                 float* __restrict__ Out, int mcols) {
  __shared__ unsigned short XH[128 * DD], XL[128 * DD];
  __shared__ unsigned short YH[128 * DD], YL[128 * DD];
  const int tid = threadIdx.x;
  const long i0 = (long)blockIdx.y * 128;
  const long j0 = (long)blockIdx.x * 128;
#pragma unroll
  for (int it = 0; it < 16; ++it) {
    int e = it * 256 + tid;
    int half = e >> 11;
    int idx = e & 2047;
    int row = idx >> 4;
    int c4 = idx & 15;
    const float* src = half ? (Y + (j0 + row) * DD) : (X + (i0 + row) * DD);
    float4 v = ((const float4*)src)[c4];
    float f[4] = {v.x, v.y, v.z, v.w};
    unsigned short h[4], l[4];
#pragma unroll
    for (int q = 0; q < 4; ++q) {
      h[q] = f2bf_rne(f[q]);
      float hv = __uint_as_float(((unsigned)h[q]) << 16);
      l[q] = f2bf_rne(f[q] - hv);
    }
    int sw = (c4 * 8) ^ ((row & 7) << 4);
    unsigned short* Ht = half ? YH : XH;
    unsigned short* Lt = half ? YL : XL;
    *(ushort4*)((char*)Ht + row * 128 + sw) = make_ushort4(h[0], h[1], h[2], h[3]);
    *(ushort4*)((char*)Lt + row * 128 + sw) = make_ushort4(l[0], l[1], l[2], l[3]);
  }
  __syncthreads();
  const int lane = tid & 63;
  const int wid = tid >> 6;
  const int wr = wid >> 1, wc = wid & 1;
  const int lr = lane & 15;
  const int hg = lane >> 4;
  f32x4 acc[4][4];
#pragma unroll
  for (int a = 0; a < 4; ++a)
#pragma unroll
    for (int c = 0; c < 4; ++c) acc[a][c] = (f32x4){0.f, 0.f, 0.f, 0.f};
  const unsigned short* At[3] = {XH, XL, XH};
  const unsigned short* Bt[3] = {YH, YH, YL};
#pragma unroll
  for (int p = 0; p < 3; ++p) {
#pragma unroll
    for (int s = 0; s < 2; ++s) {
      const int kbyte = s * 64 + hg * 16;
      short8 af[4], bfv[4];
#pragma unroll
      for (int m2 = 0; m2 < 4; ++m2) {
        int row = wr * 64 + m2 * 16 + lr;
        af[m2] = *(const short8*)((const char*)At[p] + row * 128 + (kbyte ^ ((row & 7) << 4)));
      }
#pragma unroll
      for (int n2 = 0; n2 < 4; ++n2) {
        int row = wc * 64 + n2 * 16 + lr;
        bfv[n2] = *(const short8*)((const char*)Bt[p] + row * 128 + (kbyte ^ ((row & 7) << 4)));
      }
#pragma unroll
      for (int m2 = 0; m2 < 4; ++m2)
#pragma unroll
        for (int n2 = 0; n2 < 4; ++n2)
          acc[m2][n2] = __builtin_amdgcn_mfma_f32_16x16x32_bf16(af[m2], bfv[n2], acc[m2][n2], 0, 0, 0);
    }
  }
  const float g = *gptr;
  float yv[4];
#pragma unroll
  for (int n2 = 0; n2 < 4; ++n2) yv[n2] = ysq[j0 + wc * 64 + n2 * 16 + lr];
#pragma unroll
  for (int m2 = 0; m2 < 4; ++m2) {
#pragma unroll
    for (int j = 0; j < 4; ++j) {
      long row = i0 + wr * 64 + m2 * 16 + hg * 4 + j;
      float xr = xsq[row];
      float* op = Out + row * (long)mcols + j0 + wc * 64 + lr;
#pragma unroll
      for (int n2 = 0; n2 < 4; ++n2) {
        float d = fmaxf(xr + yv[n2] - 2.0f * acc[m2][n2][j], 0.f);
        op[n2 * 16] = __expf(-g * d);
      }
    }
  }
}

extern "C" void kernel_launch(void* const* d_in, const int* in_sizes, int n_in,
                              void* d_out, int out_size, void* d_ws, size_t ws_size,
                              hipStream_t stream) {
  const float* x = (const float*)d_in[0];
  const float* y = (const float*)d_in[1];
  const float* g = (const float*)d_in[2];
  float* out = (float*)d_out;

  const int n = in_sizes[0] / DD;   // 8192
  const int m = in_sizes[1] / DD;   // 8192

  const size_t needed = (size_t)n * DD * 2 + (size_t)m * DD * 4 + (size_t)(n + m) * 4;

  if (ws_size >= needed && (n % (BM * IPB)) == 0 && (m % (2 * BN)) == 0) {
    half8* XHf = (half8*)d_ws;                          // n*DD fp16
    unsigned short* YHg = (unsigned short*)((char*)d_ws + (size_t)n * DD * 2);
    unsigned short* YLg = YHg + (size_t)m * DD;
    float* xsq = (float*)(YLg + (size_t)m * DD);
    float* ysq = xsq + n;
    prep_f16<<<(n + m) * 8 / 256, 256, 0, stream>>>(x, y, XHf, YHg, YLg, xsq, ysq, n);
    dim3 grid(m / (2 * BN), n / (BM * IPB));   // 32 x 16 = 512 blocks (2/CU)
    rbf_f16<<<grid, 256, 0, stream>>>(XHf, YHg, YLg, g, xsq, ysq, out, m);
  } else {
    float* xsq = (float*)d_ws;
    float* ysq = xsq + n;
    prep_sq<<<(n + m) / 16, 256, 0, stream>>>(x, y, xsq, ysq, n);
    dim3 grid2(m / 128, n / 128);
    rbf_mfma_fb<<<grid2, 256, 0, stream>>>(x, y, g, xsq, ysq, out, m);
  }
}

// Round 22
// 49.118 us; speedup vs baseline: 1.2156x; 1.0038x over previous
//
#include <hip/hip_runtime.h>
#include <hip/hip_bf16.h>

// RBF kernel matrix: out[i][j] = exp(-gamma * max(x2[i] + y2[j] - 2*x.y, 0))
//
// Round 22: r21 (49.3us) + A-PREFETCH HOISTED above panel stores.
// vmcnt retires in ISSUE ORDER: r21 loaded A(p+1) after panel p's 32 stores,
// so the wait before p+1's first MFMA was effectively vmcnt(0) -> drained
// all older stores (3 full per-wave drains per block). Now the 16 A(p+1)
// loads issue at the TOP of panel p (before any store): the wait at p+1 is
// vmcnt(32), satisfied with all 32 stores still in flight. Double-buffered
// A regs (afA/afB, parity-selected in a fully-unrolled p-loop; +32 VGPR).
// FP16 asymmetric 2-pass split (xh.(yh+yl), drop xl.y; ~3.4e-21 abs err),
// persistent i-sweep (IPB=4), Y strip staged once, zero post-sync barriers,
// fenced sub-tile stores: all unchanged from r21.

#define DD 64
#define BM 128
#define BN 128
#define IPB 4

typedef __attribute__((ext_vector_type(8))) _Float16 half8;
typedef __attribute__((ext_vector_type(4))) float f32x4;

#if __has_builtin(__builtin_amdgcn_exp2f)
#define EXP2(x) __builtin_amdgcn_exp2f(x)
#else
#define EXP2(x) exp2f(x)
#endif

// X fragment-linear index (half8 units): panel p, k-step s, row-block rb.
// Lane hg*16+lr holds row rb*16+lr, k = s*32+hg*8 .. +8.  (r5-verified)
__device__ __forceinline__ long fidx(int p, int s, int rb) {
  return ((((long)p * 2 + s) * 8) + rb) * 64;
}

// ---------------- prep: norms + X->fp16 frag-linear, Y->fp16 hi/lo images ---
__global__ __launch_bounds__(256)
void prep_f16(const float* __restrict__ X, const float* __restrict__ Y,
              half8* __restrict__ XHf,
              unsigned short* __restrict__ YHg, unsigned short* __restrict__ YLg,
              float* __restrict__ xsq, float* __restrict__ ysq, int n) {
  int t = blockIdx.x * 256 + threadIdx.x;
  int row_g = t >> 3;
  int chunk = t & 7;                 // 8 consecutive k per thread
  int isX = (row_g < n);
  int r = isX ? row_g : row_g - n;
  const float* src = (isX ? X : Y) + (long)r * DD + chunk * 8;
  float4 v0 = ((const float4*)src)[0];
  float4 v1 = ((const float4*)src)[1];
  float f[8] = {v0.x, v0.y, v0.z, v0.w, v1.x, v1.y, v1.z, v1.w};

  half8 h8, l8;
  float ss = 0.f;
#pragma unroll
  for (int q = 0; q < 8; ++q) {
    _Float16 h = (_Float16)f[q];          // RNE fp32->fp16
    h8[q] = h;
    l8[q] = (_Float16)(f[q] - (float)h);  // residual
    ss = fmaf(f[q], f[q], ss);
  }
  if (isX) {
    int pn = r >> 7, rb = (r >> 4) & 7, lr = r & 15;
    int s = chunk >> 2, hg = chunk & 3;
    XHf[fidx(pn, s, rb) + hg * 16 + lr] = h8;   // only hi needed for X
  } else {
    int sw = (chunk * 16) ^ ((r & 7) << 4);     // swizzled byte offset (verified)
    *(half8*)((char*)YHg + (long)r * 128 + sw) = h8;
    *(half8*)((char*)YLg + (long)r * 128 + sw) = l8;
  }
  ss += __shfl_xor(ss, 1);
  ss += __shfl_xor(ss, 2);
  ss += __shfl_xor(ss, 4);
  if (chunk == 0) (isX ? xsq : ysq)[r] = ss;
}

// ---------------- main: persistent i-sweep, prefetched A, fenced stores -----
__global__ __launch_bounds__(256, 2)
void rbf_f16p(const half8* __restrict__ XHf,
              const unsigned short* __restrict__ YHg, const unsigned short* __restrict__ YLg,
              const float* __restrict__ gptr,
              const float* __restrict__ xsq, const float* __restrict__ ysq,
              float* __restrict__ Out, int mcols) {
  // [0,16K) Y0H  [16K,32K) Y0L  [32K,48K) Y1H  [48K,64K) Y1L — never rewritten
  __shared__ __align__(128) char lds[65536];

  const int tid = threadIdx.x;
  const int lane = tid & 63;
  const int wid = tid >> 6;        // 0..3
  const int ig0 = blockIdx.y * IPB;              // first X panel
  const long j0 = (long)blockIdx.x * (2 * BN);   // 256-col strip

  // ---- prologue DMA: Y0H, Y0L, Y1H, Y1L (16 KB each)
  const char* srcs[4] = {(const char*)YHg + j0 * 128,        (const char*)YLg + j0 * 128,
                         (const char*)YHg + (j0 + BN) * 128, (const char*)YLg + (j0 + BN) * 128};
#pragma unroll
  for (int t4 = 0; t4 < 4; ++t4) {
#pragma unroll
    for (int it = 0; it < 4; ++it) {
      int off = it * 4096 + wid * 1024;           // wave-uniform
      __builtin_amdgcn_global_load_lds(
          (const __attribute__((address_space(1))) void*)(srcs[t4] + off + lane * 16),
          (__attribute__((address_space(3))) void*)(lds + t4 * 16384 + off),
          16, 0, 0);
    }
  }

  const int wr = wid >> 1, wc = wid & 1;
  const int lr = lane & 15;
  const int hg = lane >> 4;        // 0..3

  // ---- A-frags (hi only) for panel 0: direct from global, frag-linear
  half8 afA[2][4], afB[2][4];      // double-buffered [s][m2] — 64 VGPR
#pragma unroll
  for (int s = 0; s < 2; ++s)
#pragma unroll
    for (int q = 0; q < 4; ++q)
      afA[s][q] = XHf[fidx(ig0, s, wr * 4 + q) + lane];

  const float g = *gptr;
  const float cf = -g * 1.4426950408889634f;   // -gamma*log2(e)
  const float nc2 = -2.0f * cf;

  __syncthreads();   // drains prologue loads only (no stores yet) — cheap

#pragma unroll
  for (int p = 0; p < IPB; ++p) {
    const int ip = ig0 + p;
    const long i0 = (long)ip * BM;
    // parity-selected buffers (p compile-time via full unroll -> static)
    const half8 (*af)[4] = (p & 1) ? afB : afA;
    half8 (*afn)[4]      = (p & 1) ? afA : afB;

    // ---- PREFETCH A(p+1) FIRST: these 16 loads are OLDER than this panel's
    // 32 stores, so the wait at p+1's first MFMA is vmcnt(32) — no drain.
    if (p + 1 < IPB) {
#pragma unroll
      for (int s = 0; s < 2; ++s)
#pragma unroll
        for (int q = 0; q < 4; ++q)
          afn[s][q] = XHf[fidx(ip + 1, s, wr * 4 + q) + lane];
    }

    float cxr[4];
#pragma unroll
    for (int m2 = 0; m2 < 4; ++m2) cxr[m2] = cf * xsq[i0 + wr * 64 + m2 * 16 + lr];

#pragma unroll
    for (int t = 0; t < 2; ++t) {
      const long jt = j0 + (long)t * BN;
      const int yb = t * 32768;

      // hoist B(t) frags (wave-local LDS reads; data never overwritten)
      half8 bfh[2][4], bfl[2][4];   // [s][n2]
#pragma unroll
      for (int s = 0; s < 2; ++s)
#pragma unroll
        for (int q = 0; q < 4; ++q) {
          int rb = wc * 64 + q * 16 + lr;
          int ob = (s * 64 + hg * 16) ^ ((rb & 7) << 4);
          bfh[s][q] = *(const half8*)(lds + yb + rb * 128 + ob);
          bfl[s][q] = *(const half8*)(lds + yb + 16384 + rb * 128 + ob);
        }

      float4 cyv[4];
#pragma unroll
      for (int n2 = 0; n2 < 4; ++n2) {
        float4 yq = *(const float4*)&ysq[jt + wc * 64 + n2 * 16 + hg * 4];
        cyv[n2] = make_float4(cf * yq.x, cf * yq.y, cf * yq.z, cf * yq.w);
      }

      // 16 fenced sub-tiles: 4 MFMAs + 4 exp + 1 float4 store each
#pragma unroll
      for (int m2 = 0; m2 < 4; ++m2) {
        long row = i0 + wr * 64 + m2 * 16 + lr;
        float* op = Out + row * (long)mcols + jt + wc * 64 + hg * 4;
#pragma unroll
        for (int n2 = 0; n2 < 4; ++n2) {
          f32x4 a = (f32x4){0.f, 0.f, 0.f, 0.f};
#pragma unroll
          for (int s = 0; s < 2; ++s) {
            a = __builtin_amdgcn_mfma_f32_16x16x32_f16(bfh[s][n2], af[s][m2], a, 0, 0, 0);
            a = __builtin_amdgcn_mfma_f32_16x16x32_f16(bfl[s][n2], af[s][m2], a, 0, 0, 0);
          }
          float o[4];
          o[0] = EXP2(fminf(fmaf(nc2, a[0], cxr[m2] + cyv[n2].x), 0.f));
          o[1] = EXP2(fminf(fmaf(nc2, a[1], cxr[m2] + cyv[n2].y), 0.f));
          o[2] = EXP2(fminf(fmaf(nc2, a[2], cxr[m2] + cyv[n2].z), 0.f));
          o[3] = EXP2(fminf(fmaf(nc2, a[3], cxr[m2] + cyv[n2].w), 0.f));
          *(float4*)(op + n2 * 16) = *(float4*)o;
          __builtin_amdgcn_sched_barrier(0);   // pin store spacing
        }
      }
    }
  }
}

// ---------------- fallback (proven round-2 path, bf16 3-pass) ---------------
typedef __attribute__((ext_vector_type(8))) short short8;

__device__ __forceinline__ unsigned short f2bf_rne(float f) {
  unsigned u = __float_as_uint(f);
  unsigned r = u + 0x7FFFu + ((u >> 16) & 1u);
  return (unsigned short)(r >> 16);
}

__global__ __launch_bounds__(256)
void prep_sq(const float* __restrict__ X, const float* __restrict__ Y,
             float* __restrict__ xsq, float* __restrict__ ysq, int n) {
  int t = blockIdx.x * 256 + threadIdx.x;
  int row = t >> 4;
  int c = t & 15;
  const float* src;
  float* dst;
  if (row < n) { src = X + (long)row * DD; dst = xsq + row; }
  else         { src = Y + (long)(row - n) * DD; dst = ysq + (row - n); }
  float4 v = ((const float4*)src)[c];
  float s = v.x * v.x + v.y * v.y + v.z * v.z + v.w * v.w;
  s += __shfl_xor(s, 1);
  s += __shfl_xor(s, 2);
  s += __shfl_xor(s, 4);
  s += __shfl_xor(s, 8);
  if (c == 0) *dst = s;
}

__global__ __launch_bounds__(256, 2)
void rbf_mfma_fb(const float* __restrict__ X, const float* __restrict__ Y,
                 const float* __restrict__ gptr,
                 const float* __restrict__ xsq, const float* __restrict__ ysq,
                 float* __restrict__ Out, int mcols) {
  __shared__ unsigned short XH[128 * DD], XL[128 * DD];
  __shared__ unsigned short YH[128 * DD], YL[128 * DD];
  const int tid = threadIdx.x;
  const long i0 = (long)blockIdx.y * 128;
  const long j0 = (long)blockIdx.x * 128;
#pragma unroll
  for (int it = 0; it < 16; ++it) {
    int e = it * 256 + tid;
    int half = e >> 11;
    int idx = e & 2047;
    int row = idx >> 4;
    int c4 = idx & 15;
    const float* src = half ? (Y + (j0 + row) * DD) : (X + (i0 + row) * DD);
    float4 v = ((const float4*)src)[c4];
    float f[4] = {v.x, v.y, v.z, v.w};
    unsigned short h[4], l[4];
#pragma unroll
    for (int q = 0; q < 4; ++q) {
      h[q] = f2bf_rne(f[q]);
      float hv = __uint_as_float(((unsigned)h[q]) << 16);
      l[q] = f2bf_rne(f[q] - hv);
    }
    int sw = (c4 * 8) ^ ((row & 7) << 4);
    unsigned short* Ht = half ? YH : XH;
    unsigned short* Lt = half ? YL : XL;
    *(ushort4*)((char*)Ht + row * 128 + sw) = make_ushort4(h[0], h[1], h[2], h[3]);
    *(ushort4*)((char*)Lt + row * 128 + sw) = make_ushort4(l[0], l[1], l[2], l[3]);
  }
  __syncthreads();
  const int lane = tid & 63;
  const int wid = tid >> 6;
  const int wr = wid >> 1, wc = wid & 1;
  const int lr = lane & 15;
  const int hg = lane >> 4;
  f32x4 acc[4][4];
#pragma unroll
  for (int a = 0; a < 4; ++a)
#pragma unroll
    for (int c = 0; c < 4; ++c) acc[a][c] = (f32x4){0.f, 0.f, 0.f, 0.f};
  const unsigned short* At[3] = {XH, XL, XH};
  const unsigned short* Bt[3] = {YH, YH, YL};
#pragma unroll
  for (int p = 0; p < 3; ++p) {
#pragma unroll
    for (int s = 0; s < 2; ++s) {
      const int kbyte = s * 64 + hg * 16;
      short8 af[4], bfv[4];
#pragma unroll
      for (int m2 = 0; m2 < 4; ++m2) {
        int row = wr * 64 + m2 * 16 + lr;
        af[m2] = *(const short8*)((const char*)At[p] + row * 128 + (kbyte ^ ((row & 7) << 4)));
      }
#pragma unroll
      for (int n2 = 0; n2 < 4; ++n2) {
        int row = wc * 64 + n2 * 16 + lr;
        bfv[n2] = *(const short8*)((const char*)Bt[p] + row * 128 + (kbyte ^ ((row & 7) << 4)));
      }
#pragma unroll
      for (int m2 = 0; m2 < 4; ++m2)
#pragma unroll
        for (int n2 = 0; n2 < 4; ++n2)
          acc[m2][n2] = __builtin_amdgcn_mfma_f32_16x16x32_bf16(af[m2], bfv[n2], acc[m2][n2], 0, 0, 0);
    }
  }
  const float g = *gptr;
  float yv[4];
#pragma unroll
  for (int n2 = 0; n2 < 4; ++n2) yv[n2] = ysq[j0 + wc * 64 + n2 * 16 + lr];
#pragma unroll
  for (int m2 = 0; m2 < 4; ++m2) {
#pragma unroll
    for (int j = 0; j < 4; ++j) {
      long row = i0 + wr * 64 + m2 * 16 + hg * 4 + j;
      float xr = xsq[row];
      float* op = Out + row * (long)mcols + j0 + wc * 64 + lr;
#pragma unroll
      for (int n2 = 0; n2 < 4; ++n2) {
        float d = fmaxf(xr + yv[n2] - 2.0f * acc[m2][n2][j], 0.f);
        op[n2 * 16] = __expf(-g * d);
      }
    }
  }
}

extern "C" void kernel_launch(void* const* d_in, const int* in_sizes, int n_in,
                              void* d_out, int out_size, void* d_ws, size_t ws_size,
                              hipStream_t stream) {
  const float* x = (const float*)d_in[0];
  const float* y = (const float*)d_in[1];
  const float* g = (const float*)d_in[2];
  float* out = (float*)d_out;

  const int n = in_sizes[0] / DD;   // 8192
  const int m = in_sizes[1] / DD;   // 8192

  const size_t needed = (size_t)n * DD * 2 + (size_t)m * DD * 4 + (size_t)(n + m) * 4;

  if (ws_size >= needed && (n % (BM * IPB)) == 0 && (m % (2 * BN)) == 0) {
    half8* XHf = (half8*)d_ws;                          // n*DD fp16
    unsigned short* YHg = (unsigned short*)((char*)d_ws + (size_t)n * DD * 2);
    unsigned short* YLg = YHg + (size_t)m * DD;
    float* xsq = (float*)(YLg + (size_t)m * DD);
    float* ysq = xsq + n;
    prep_f16<<<(n + m) * 8 / 256, 256, 0, stream>>>(x, y, XHf, YHg, YLg, xsq, ysq, n);
    dim3 grid(m / (2 * BN), n / (BM * IPB));   // 32 x 16 = 512 blocks (2/CU)
    rbf_f16p<<<grid, 256, 0, stream>>>(XHf, YHg, YLg, g, xsq, ysq, out, m);
  } else {
    float* xsq = (float*)d_ws;
    float* ysq = xsq + n;
    prep_sq<<<(n + m) / 16, 256, 0, stream>>>(x, y, xsq, ysq, n);
    dim3 grid2(m / 128, n / 128);
    rbf_mfma_fb<<<grid2, 256, 0, stream>>>(x, y, g, xsq, ysq, out, m);
  }
}